// Round 6
// baseline (92.333 us; speedup 1.0000x reference)
//
#include <hip/hip_runtime.h>
#include <hip/hip_bf16.h>

// B=8192 rows, N=64 nodes, C=256. Per node: MLP 1->C->C->1 on s=Q*Y,
// then softmax over [z0, z_1..z_64] per row. Output f32 [B, 65].
//
// Round 6: break the 2-wave/SIMD barrier lockstep.
//  - 256-thread blocks (4 waves, 1x4 col-split), BM=64 tiles, 2 blocks/CU
//    (LDS 71.8KB) -> the 2 waves/SIMD (VGPR-capped) are from DIFFERENT
//    blocks with independent barriers -> stalls of one hide under the other.
//  - explicit afr software pipeline: read ks+1 frags before MFMA(ks)
//  - next-tile s-values batch-loaded to regs at tile top
//  - grid (64 nodes, 8 chunks): same-node blocks = same XCD (ids = mod 64)

#define BM 64
#define CHUNK 1024
#define NTILES 16
#define PANEL 4104   // (64*64 + 8) shorts per K-panel; same conflict-free family as R3-R5

typedef __attribute__((ext_vector_type(8))) short bf16x8;
typedef __attribute__((ext_vector_type(4))) float f32x4;

__device__ __forceinline__ unsigned short f2bf(float f) {
    unsigned int u = __float_as_uint(f);
    u += 0x7FFFu + ((u >> 16) & 1u);   // RNE
    return (unsigned short)(u >> 16);
}

// dst.lo = bf16(a), dst.hi = bf16(b) — single HW instruction
__device__ __forceinline__ unsigned int cvtpk(float a, float b) {
    unsigned int r;
    asm("v_cvt_pk_bf16_f32 %0, %1, %2" : "=v"(r) : "v"(a), "v"(b));
    return r;
}

// sum across the 16 lanes of each DPP row
__device__ __forceinline__ float row_reduce16(float x) {
    int v;
    v = __builtin_amdgcn_update_dpp(0, __float_as_int(x), 0xB1, 0xF, 0xF, false);  // quad_perm [1,0,3,2]
    x += __int_as_float(v);
    v = __builtin_amdgcn_update_dpp(0, __float_as_int(x), 0x4E, 0xF, 0xF, false);  // quad_perm [2,3,0,1]
    x += __int_as_float(v);
    v = __builtin_amdgcn_update_dpp(0, __float_as_int(x), 0x124, 0xF, 0xF, false); // row_ror:4
    x += __int_as_float(v);
    v = __builtin_amdgcn_update_dpp(0, __float_as_int(x), 0x128, 0xF, 0xF, false); // row_ror:8
    x += __int_as_float(v);
    return x;
}

// ---------------------------------------------------------------------------
// Kernel 0: W2 [N][C][D] f32 -> W2t [N][D][C] bf16 (K-contiguous for MFMA B).
// ---------------------------------------------------------------------------
__global__ __launch_bounds__(256) void transpose_w2(
    const float* __restrict__ W2, unsigned short* __restrict__ W2t)
{
    __shared__ float tile[32][33];
    const int n  = blockIdx.z;
    const int c0 = blockIdx.y << 5;
    const int d0 = blockIdx.x << 5;
    const int tx = threadIdx.x & 31;
    const int ty = threadIdx.x >> 5;
    const float* src = W2 + ((size_t)n << 16);
    #pragma unroll
    for (int j = 0; j < 32; j += 8)
        tile[ty + j][tx] = src[(size_t)(c0 + ty + j) * 256 + d0 + tx];
    __syncthreads();
    unsigned short* dst = W2t + ((size_t)n << 16);
    #pragma unroll
    for (int j = 0; j < 32; j += 8)
        dst[(size_t)(d0 + ty + j) * 256 + c0 + tx] = f2bf(tile[tx][ty + j]);
}

// ---------------------------------------------------------------------------
// Kernel 0b: S[n][b] = Q[b][n]*Y[b][n]  (node-major, 64x64 LDS transpose)
// ---------------------------------------------------------------------------
__global__ __launch_bounds__(256) void make_s(
    const float* __restrict__ Q, const float* __restrict__ Y,
    float* __restrict__ S)
{
    __shared__ float ts[64][65];
    const int b0 = blockIdx.x << 6;
    #pragma unroll
    for (int jj = 0; jj < 16; jj++) {
        int idx = threadIdx.x + (jj << 8);
        int r = idx >> 6, c = idx & 63;
        ts[r][c] = Q[(size_t)(b0 + r) * 64 + c] * Y[(size_t)(b0 + r) * 64 + c];
    }
    __syncthreads();
    #pragma unroll
    for (int jj = 0; jj < 16; jj++) {
        int idx = threadIdx.x + (jj << 8);
        int nn = idx >> 6, bb = idx & 63;
        S[((size_t)nn << 13) + b0 + bb] = ts[bb][nn];
    }
}

// ---------------------------------------------------------------------------
// Kernel 1: W2-resident fused MLP GEMM.
// grid (64 nodes, 8 chunks), 256 thr = 4 waves; wave wc owns 64 rows x 64 cols.
// breg[4][8]=128 regs; acc[4][4]; A-tile 64x256 double-buffered (65.7KB LDS).
// ---------------------------------------------------------------------------
__global__ __launch_bounds__(256, 2) void gemm_node(
    const float* __restrict__ S,
    const float* __restrict__ W1, const float* __restrict__ b1,
    const unsigned short* __restrict__ W2t,
    const float* __restrict__ b2, const float* __restrict__ W3,
    const float* __restrict__ b3, float* __restrict__ Z)
{
    __shared__ short sA[2][4 * PANEL];    // 65,664 B, double-buffered A
    __shared__ float zpart[2][4][BM];     // 2,048 B  (wc-major)
    __shared__ float s_lds[CHUNK];        // 4,096 B

    const int tid  = threadIdx.x;
    const int lane = tid & 63;
    const int wc   = tid >> 6;            // 0..3 : col quarter (64 cols)
    const int n    = blockIdx.x;
    const int cr0  = blockIdx.y * CHUNK;

    // staging: fixed 8-short k-window, rows r0 + 8*ks (ks=0..7)
    const int r0  = tid >> 5;             // 0..7
    const int kc  = (tid & 31) << 3;      // 0..248
    const int stBase = (kc >> 6) * PANEL + (r0 << 6) + ((kc & 63) ^ ((r0 & 7) << 3));

    // A-read lane base (swizzle folded; per-(m,ks) parts are immediates)
    const int aE = ((lane & 15) << 6)
                 + ((((lane >> 4) << 3)) ^ ((lane & 3) << 3))
                 + ((lane & 4) << 3);
    const int aO = aE ^ 32;

    const float* W1n = W1 + n * 256;
    const float* b1n = b1 + n * 256;
    const unsigned short* W2n = W2t + ((size_t)n << 16);
    const float* Sn = S + ((size_t)n << 13);
    float* Zn = Z + ((size_t)n << 13);

    // ---- fill s_lds: one coalesced float4 per thread ----
    {
        float4 v = *reinterpret_cast<const float4*>(Sn + cr0 + (tid << 2));
        *reinterpret_cast<float4*>(&s_lds[tid << 2]) = v;
    }

    // ---- hoisted per-thread W1/b1 window (16 regs) ----
    float pw1[8], pb1[8];
    {
        float4 wa = *reinterpret_cast<const float4*>(&W1n[kc]);
        float4 wb = *reinterpret_cast<const float4*>(&W1n[kc + 4]);
        float4 ba = *reinterpret_cast<const float4*>(&b1n[kc]);
        float4 bb = *reinterpret_cast<const float4*>(&b1n[kc + 4]);
        pw1[0]=wa.x; pw1[1]=wa.y; pw1[2]=wa.z; pw1[3]=wa.w;
        pw1[4]=wb.x; pw1[5]=wb.y; pw1[6]=wb.z; pw1[7]=wb.w;
        pb1[0]=ba.x; pb1[1]=ba.y; pb1[2]=ba.z; pb1[3]=ba.w;
        pb1[4]=bb.x; pb1[5]=bb.y; pb1[6]=bb.z; pb1[7]=bb.w;
    }

    // ---- B fragments: wave's 64-col slice of W2[n] in regs (128 VGPR) ----
    bf16x8 breg[4][8];
    #pragma unroll
    for (int p = 0; p < 4; p++)
        #pragma unroll
        for (int ks = 0; ks < 8; ks++) {
            int col = (wc << 6) + (p << 4) + (lane & 15);
            int k   = (ks << 5) + ((lane >> 4) << 3);
            breg[p][ks] = *reinterpret_cast<const bf16x8*>(&W2n[(size_t)col * 256 + k]);
        }

    // ---- hoisted epilogue constants ----
    float w3v[4], b2v[4];
    #pragma unroll
    for (int p = 0; p < 4; p++) {
        int d = (wc << 6) + (p << 4) + (lane & 15);
        w3v[p] = W3[n * 256 + d];
        b2v[p] = b2[n * 256 + d];
    }
    const float b3n = b3[n];

    __syncthreads();   // s_lds ready

    // ---- prologue: stage tile 0 into buf 0 ----
    {
        short* bW = (short*)sA[0] + stBase;
        #pragma unroll
        for (int ks = 0; ks < 8; ks++) {
            const float sv = s_lds[r0 + (ks << 3)];
            float h[8];
            #pragma unroll
            for (int i = 0; i < 8; i++)
                h[i] = fmaxf(fmaf(sv, pw1[i], pb1[i]), 0.f);
            uint4 wv;
            wv.x = cvtpk(h[0], h[1]); wv.y = cvtpk(h[2], h[3]);
            wv.z = cvtpk(h[4], h[5]); wv.w = cvtpk(h[6], h[7]);
            *reinterpret_cast<uint4*>(bW + (ks << 9)) = wv;   // rows step by 8 -> 8*64 shorts
        }
    }
    __syncthreads();   // tile 0 staged

    int cur = 0;
    for (int t = 0; t < NTILES; t++) {
        const short* bR = sA[cur];
        short* bW = (short*)sA[cur ^ 1] + stBase;

        // batch-load next tile's s values (8 independent LDS reads)
        float sv8[8];
        {
            const float* sp = &s_lds[(((t + 1) & 15) << 6) + r0];
            #pragma unroll
            for (int ks = 0; ks < 8; ks++) sv8[ks] = sp[ks << 3];
        }

        f32x4 acc[4][4] = {};
        bf16x8 afr[4], afrN[4];

        // preload ks=0 fragments
        {
            const short* ab = bR + aE;
            #pragma unroll
            for (int m = 0; m < 4; m++)
                afr[m] = *reinterpret_cast<const bf16x8*>(ab + (m << 10));
        }

        #pragma unroll
        for (int ks = 0; ks < 8; ks++) {
            // prefetch next k-slice fragments (hidden under this MFMA cluster)
            if (ks < 7) {
                const int kn = ks + 1;
                const short* ab = bR + ((kn & 1) ? aO : aE) + (kn >> 1) * PANEL;
                #pragma unroll
                for (int m = 0; m < 4; m++)
                    afrN[m] = *reinterpret_cast<const bf16x8*>(ab + (m << 10));
            }
            // stage row r0+8*ks of tile t+1
            {
                const float sv = sv8[ks];
                float h[8];
                #pragma unroll
                for (int i = 0; i < 8; i++)
                    h[i] = fmaxf(fmaf(sv, pw1[i], pb1[i]), 0.f);
                uint4 wv;
                wv.x = cvtpk(h[0], h[1]); wv.y = cvtpk(h[2], h[3]);
                wv.z = cvtpk(h[4], h[5]); wv.w = cvtpk(h[6], h[7]);
                *reinterpret_cast<uint4*>(bW + (ks << 9)) = wv;
            }
            __builtin_amdgcn_s_setprio(1);
            #pragma unroll
            for (int m = 0; m < 4; m++)
                #pragma unroll
                for (int p = 0; p < 4; p++)
                    acc[m][p] = __builtin_amdgcn_mfma_f32_16x16x32_bf16(
                        afr[m], breg[p][ks], acc[m][p], 0, 0, 0);
            __builtin_amdgcn_s_setprio(0);
            #pragma unroll
            for (int m = 0; m < 4; m++) afr[m] = afrN[m];
        }

        // ---- epilogue: pz = sum_d relu(acc + b2) * w3, DPP 16-lane reduce ----
        #pragma unroll
        for (int m = 0; m < 4; m++) {
            f32x4 pzv = {0.f, 0.f, 0.f, 0.f};
            #pragma unroll
            for (int p = 0; p < 4; p++)
                #pragma unroll
                for (int j = 0; j < 4; j++)
                    pzv[j] = fmaf(fmaxf(acc[m][p][j] + b2v[p], 0.f), w3v[p], pzv[j]);
            #pragma unroll
            for (int j = 0; j < 4; j++) pzv[j] = row_reduce16(pzv[j]);
            if ((lane & 15) == 0)
                *reinterpret_cast<f32x4*>(
                    &zpart[cur][wc][(m << 4) + ((lane >> 4) << 2)]) = pzv;
        }
        __syncthreads();
        if (tid < BM) {
            float z = zpart[cur][0][tid] + zpart[cur][1][tid]
                    + zpart[cur][2][tid] + zpart[cur][3][tid] + b3n;
            Zn[cr0 + (t << 6) + tid] = z;   // coalesced (node-major)
        }
        cur ^= 1;
    }
}

// ---------------------------------------------------------------------------
// Kernel 2: per-row 65-way softmax. One wave per batch row (lane = node).
// Z node-major: Z[n][b].
// ---------------------------------------------------------------------------
__global__ __launch_bounds__(256) void softmax_rows(
    const float* __restrict__ Q, const float* __restrict__ Y,
    const float* __restrict__ Z, const float* __restrict__ bias0,
    float* __restrict__ out)
{
    const int lane = threadIdx.x & 63;
    const int wv   = threadIdx.x >> 6;
    const int b    = (blockIdx.x << 2) + wv;

    float s = Q[(size_t)b * 64 + lane] * Y[(size_t)b * 64 + lane];
    float ssum = s;
    #pragma unroll
    for (int mask = 32; mask >= 1; mask >>= 1) ssum += __shfl_xor(ssum, mask, 64);
    const float z0 = bias0[0] - ssum;

    float zl = Z[((size_t)lane << 13) + b];
    float mx = zl;
    #pragma unroll
    for (int mask = 32; mask >= 1; mask >>= 1) mx = fmaxf(mx, __shfl_xor(mx, mask, 64));
    mx = fmaxf(mx, z0);

    float el = expf(zl - mx);
    float e0 = expf(z0 - mx);
    float den = el;
    #pragma unroll
    for (int mask = 32; mask >= 1; mask >>= 1) den += __shfl_xor(den, mask, 64);
    den += e0;
    const float inv = 1.0f / den;

    out[(size_t)b * 65 + 1 + lane] = el * inv;
    if (lane == 0) out[(size_t)b * 65] = e0 * inv;
}

// ---------------------------------------------------------------------------
extern "C" void kernel_launch(void* const* d_in, const int* in_sizes, int n_in,
                              void* d_out, int out_size, void* d_ws, size_t ws_size,
                              hipStream_t stream)
{
    const float* Q     = (const float*)d_in[0];
    const float* Y     = (const float*)d_in[1];
    const float* W1    = (const float*)d_in[2];
    const float* b1    = (const float*)d_in[3];
    const float* W2    = (const float*)d_in[4];
    const float* b2    = (const float*)d_in[5];
    const float* W3    = (const float*)d_in[6];
    const float* b3    = (const float*)d_in[7];
    const float* bias0 = (const float*)d_in[8];
    float* out = (float*)d_out;

    // ws: W2t bf16 8.39MB | Z f32 node-major 2.10MB | S f32 node-major 2.10MB
    unsigned short* W2t = (unsigned short*)d_ws;
    float* Z = (float*)((char*)d_ws + (size_t)8388608);
    float* S = (float*)((char*)d_ws + (size_t)8388608 + 2097152);

    transpose_w2<<<dim3(8, 8, 64), 256, 0, stream>>>(W2, W2t);
    make_s<<<128, 256, 0, stream>>>(Q, Y, S);
    gemm_node<<<dim3(64, 8), 256, 0, stream>>>(S, W1, b1, W2t, b2, W3, b3, Z);
    softmax_rows<<<2048, 256, 0, stream>>>(Q, Y, Z, bias0, out);
}